// Round 1
// baseline (255.648 us; speedup 1.0000x reference)
//
#include <hip/hip_runtime.h>

// InterNet B=32,N=16,D=64,P=8. Factorized: conv(mask*[y1;y2],W_rel) =
// mask*(convA(x[o1]) + convB(x[o2])).
// R16: fuse k1+k2 into one cooperative kernel with a per-batch device-scope
// handshake (release atomicAdd / acquire spin on cnt[b]); x staged ONCE into
// the [a|x] LDS layout and reused by rel/self/agg; self-conv overlaps the
// handshake wait; agg conv uses swapped MFMA operands so the fp32 output is
// written as coalesced float4 per thread. Fallback to the 3-kernel path if
// cooperative launch is unavailable under graph capture.
//   prep_w: weights -> bf16 Wt [tap][oc][ic]; zeros the 32 batch counters.
//   kfused: stage x -> rel convs -> cA/cB (bf16, HBM/L2) -> signal ->
//           self conv (overlap) -> wait batch -> combine -> aff -> agg -> out

#define NIMG 512
#define IMGSZ 4096

using bf16x8 = __attribute__((ext_vector_type(8))) short;
using f32x4  = __attribute__((ext_vector_type(4))) float;

__device__ inline unsigned short f2bf(float f) {
  union { float f; unsigned u; } v; v.f = f;
  unsigned r = v.u + 0x7fffu + ((v.u >> 16) & 1u);
  return (unsigned short)(r >> 16);
}

__device__ inline f32x4 bf4_to_f32(uint2 p) {
  union { unsigned u; float f; } c;
  f32x4 r;
  c.u = (p.x & 0xffffu) << 16;  r[0] = c.f;
  c.u = (p.x & 0xffff0000u);    r[1] = c.f;
  c.u = (p.y & 0xffffu) << 16;  r[2] = c.f;
  c.u = (p.y & 0xffff0000u);    r[3] = c.f;
  return r;
}

// Wt slots: self [9][64][64] @0, aff @36864, rel [9][64][128] @73728,
//           agg [9][64][128] @147456.
__global__ __launch_bounds__(256) void prep_w(
    const float* __restrict__ Wr, const float* __restrict__ Ws,
    const float* __restrict__ Wa, const float* __restrict__ Wg,
    unsigned short* __restrict__ Wt, int* __restrict__ cnt)
{
  if (blockIdx.x == 0 && threadIdx.x < 32) cnt[threadIdx.x * 32] = 0;
  int idx = blockIdx.x * 256 + threadIdx.x;
  if (idx >= 221184) return;
  float v;
  if (idx < 73728) {
    int c = idx / 36864, r = idx % 36864;
    int t = r >> 12, oc = (r >> 6) & 63, ic = r & 63;
    v = (c == 0 ? Ws : Wa)[oc * 576 + ic * 9 + t];
  } else {
    int r2 = idx - 73728;
    int half = r2 / 73728, rr = r2 % 73728;
    int t = rr >> 13, oc = (rr >> 7) & 63, ic = rr & 127;
    v = (half ? Wg : Wr)[oc * 1152 + ic * 9 + t];
  }
  Wt[idx] = f2bf(v);
}

// batch b pinned to XCD b&7 (perf heuristic; correctness never depends on it)
__device__ inline void decode_img(int j, int& b, int& o) {
  b = ((j >> 7) << 3) | (j & 7);
  o = (j >> 3) & 15;
}

// stage x (fp32 [ic][px]) -> LDS bf16 [px][stride ROWX], cols at +coff.
template<int ROWX>
__device__ inline void stage_x(const float* __restrict__ xb,
                               unsigned short* __restrict__ s,
                               int coff, int w, int px) {
#pragma unroll
  for (int r = 0; r < 8; ++r) {
    int ic0 = (w + 4 * r) * 2;
    const float* sp = xb + ic0 * 64;
    float a = sp[px], c = sp[64 + px];
    *(unsigned*)(s + px * ROWX + coff + ic0) =
        (unsigned)f2bf(a) | ((unsigned)f2bf(c) << 16);
  }
}

// ---------------------------------------------------------------- fused
__global__ __launch_bounds__(256, 2) void kfused(
    const float* __restrict__ x,
    const int* __restrict__ g_idx,
    const unsigned short* __restrict__ Wt,
    const float* __restrict__ b_rel, const float* __restrict__ b_self,
    const float* __restrict__ b_aff, const float* __restrict__ b_agg,
    unsigned short* __restrict__ cA, unsigned short* __restrict__ cB,
    int* __restrict__ cnt,
    float* __restrict__ out)
{
  constexpr int ROW = 72, ROW2 = 136, XROW = 68;
  __shared__ __align__(16) unsigned short sX[65 * ROW2];   // [a | x] bf16
  __shared__ __align__(16) unsigned short sPred[65 * ROW]; // pred bf16
  __shared__ __align__(16) float sXS[64 * XROW];           // xs fp32
  __shared__ int so1[15], so2[15];
  __shared__ float sm[15];

  int b, i;
  decode_img(blockIdx.x, b, i);
  const int img = b * 16 + i;
  const int tid = threadIdx.x;
  const int w = tid >> 6, lane = tid & 63;
  const int b32 = b * 32;

  if (tid < 15) {
    const int* gp = g_idx + ((size_t)b * 240 + i * 15 + tid) * 3;
    so1[tid] = gp[0] & 15;   // tile(x, n-1): x1[j] = x[j % 16]
    so2[tid] = gp[1] & 15;
    sm[tid]  = (float)gp[2];
  }

  stage_x<ROW2>(x + (size_t)img * IMGSZ, sX, 64, w, lane);
  if (tid < 68) ((unsigned*)(sX + 64 * ROW2))[tid] = 0;
  if (tid < 36) ((unsigned*)(sPred + 64 * ROW))[tid] = 0;
  __syncthreads();

  const int q = lane >> 4, n16 = lane & 15;
  const int ocb = w * 16;
  const int co = ocb + q * 4;
  const int aw64  = (ocb + n16) * 64 + q * 8;
  const int aw128 = (ocb + n16) * 128 + q * 8;

  int pyt[4], pxt[4];
#pragma unroll
  for (int t = 0; t < 4; ++t) { int p = t * 16 + n16; pyt[t] = p >> 3; pxt[t] = p & 7; }

  // ---- phase 1: rel convs (from staged x at cols 64..127) -> cA/cB bf16
  {
    f32x4 aA[4] = {}, aB[4] = {};
    const unsigned short* WA = Wt + 73728 + aw128;  // rel ic 0..63
    const unsigned short* WB = WA + 64;             // rel ic 64..127
#pragma unroll
    for (int tap = 0; tap < 9; ++tap) {
      const int dy = tap / 3 - 1, dx = tap % 3 - 1;
      int spt[4];
#pragma unroll
      for (int t = 0; t < 4; ++t) {
        int sy = pyt[t] + dy, sx = pxt[t] + dx;
        spt[t] = ((unsigned)sy < 8u && (unsigned)sx < 8u) ? (sy * 8 + sx) : 64;
      }
#pragma unroll
      for (int ks = 0; ks < 2; ++ks) {
        bf16x8 aa = *(const bf16x8*)(WA + tap * 8192 + ks * 32);
        bf16x8 ab = *(const bf16x8*)(WB + tap * 8192 + ks * 32);
#pragma unroll
        for (int t = 0; t < 4; ++t) {
          bf16x8 bt = *(const bf16x8*)(sX + spt[t] * ROW2 + 64 + ks * 32 + q * 8);
          aA[t] = __builtin_amdgcn_mfma_f32_16x16x32_bf16(aa, bt, aA[t], 0, 0, 0);
          aB[t] = __builtin_amdgcn_mfma_f32_16x16x32_bf16(ab, bt, aB[t], 0, 0, 0);
        }
      }
    }
    const size_t ib = (size_t)img * IMGSZ;
#pragma unroll
    for (int t = 0; t < 4; ++t) {
      int p = t * 16 + n16;
      uint2 pa, pb;
      pa.x = (unsigned)f2bf(aA[t][0]) | ((unsigned)f2bf(aA[t][1]) << 16);
      pa.y = (unsigned)f2bf(aA[t][2]) | ((unsigned)f2bf(aA[t][3]) << 16);
      pb.x = (unsigned)f2bf(aB[t][0]) | ((unsigned)f2bf(aB[t][1]) << 16);
      pb.y = (unsigned)f2bf(aB[t][2]) | ((unsigned)f2bf(aB[t][3]) << 16);
      *(uint2*)(cA + ib + p * 64 + co) = pa;
      *(uint2*)(cB + ib + p * 64 + co) = pb;
    }
  }

  // release: make cA/cB agent-visible, then signal this batch's counter
  __threadfence();
  __syncthreads();
  if (tid == 0)
    __hip_atomic_fetch_add(cnt + b32, 1, __ATOMIC_RELEASE, __HIP_MEMORY_SCOPE_AGENT);

  // ---- self conv -> xs in LDS fp32 (no sibling dep: overlaps handshake)
  {
    f32x4 f[4] = {};
    const unsigned short* WS = Wt + aw64;
#pragma unroll
    for (int tap = 0; tap < 9; ++tap) {
      const int dy = tap / 3 - 1, dx = tap % 3 - 1;
      int spt[4];
#pragma unroll
      for (int t = 0; t < 4; ++t) {
        int sy = pyt[t] + dy, sx = pxt[t] + dx;
        spt[t] = ((unsigned)sy < 8u && (unsigned)sx < 8u) ? (sy * 8 + sx) : 64;
      }
#pragma unroll
      for (int ks = 0; ks < 2; ++ks) {
        bf16x8 a = *(const bf16x8*)(WS + tap * 4096 + ks * 32);
#pragma unroll
        for (int t = 0; t < 4; ++t) {
          bf16x8 bt = *(const bf16x8*)(sX + spt[t] * ROW2 + 64 + ks * 32 + q * 8);
          f[t] = __builtin_amdgcn_mfma_f32_16x16x32_bf16(a, bt, f[t], 0, 0, 0);
        }
      }
    }
#pragma unroll
    for (int t = 0; t < 4; ++t) {
      int p = t * 16 + n16;
      f32x4 vs = f[t];
#pragma unroll
      for (int r = 0; r < 4; ++r) vs[r] = fmaxf(vs[r] + b_self[co + r], 0.f);
      *(f32x4*)(sXS + p * XROW + co) = vs;
    }
  }

  // acquire: wait for all 16 siblings of this batch
  if (tid == 0) {
    while (__hip_atomic_load(cnt + b32, __ATOMIC_ACQUIRE, __HIP_MEMORY_SCOPE_AGENT) < 16)
      __builtin_amdgcn_s_sleep(2);
  }
  __syncthreads();
  __threadfence();

  // ---- combine: pred = xs + sum_j relu(m_j*(cA[o1_j]+cB[o2_j]) + br)
  {
    const size_t bb = (size_t)b * 16 * IMGSZ;
#pragma unroll 1
    for (int pass = 0; pass < 4; ++pass) {
      const int e = tid * 4 + pass * 1024;   // 4 consecutive [px][ic] elems
      const int e_px = e >> 6, e_ic = e & 63;
      uint2 v1[15], v2[15];
#pragma unroll
      for (int j = 0; j < 15; ++j) {
        v1[j] = *(const uint2*)(cA + bb + (size_t)so1[j] * IMGSZ + e);
        v2[j] = *(const uint2*)(cB + bb + (size_t)so2[j] * IMGSZ + e);
      }
      f32x4 xv = *(const f32x4*)(sXS + e_px * XROW + e_ic);
      float acc[4], br[4];
#pragma unroll
      for (int r = 0; r < 4; ++r) { br[r] = b_rel[e_ic + r]; acc[r] = xv[r]; }
#pragma unroll
      for (int j = 0; j < 15; ++j) {
        float m = sm[j];
        f32x4 a1 = bf4_to_f32(v1[j]);
        f32x4 a2 = bf4_to_f32(v2[j]);
#pragma unroll
        for (int r = 0; r < 4; ++r)
          acc[r] += fmaxf(m * (a1[r] + a2[r]) + br[r], 0.f);
      }
      uint2 pk;
      pk.x = (unsigned)f2bf(acc[0]) | ((unsigned)f2bf(acc[1]) << 16);
      pk.y = (unsigned)f2bf(acc[2]) | ((unsigned)f2bf(acc[3]) << 16);
      *(uint2*)(sPred + e_px * ROW + e_ic) = pk;
    }
  }
  __syncthreads();

  // ---- aff conv: sPred -> a -> sX cols 0..63
  {
    f32x4 f[4] = {};
    const unsigned short* WA = Wt + 36864 + aw64;
#pragma unroll
    for (int tap = 0; tap < 9; ++tap) {
      const int dy = tap / 3 - 1, dx = tap % 3 - 1;
      int spt[4];
#pragma unroll
      for (int t = 0; t < 4; ++t) {
        int sy = pyt[t] + dy, sx = pxt[t] + dx;
        spt[t] = ((unsigned)sy < 8u && (unsigned)sx < 8u) ? (sy * 8 + sx) : 64;
      }
#pragma unroll
      for (int ks = 0; ks < 2; ++ks) {
        bf16x8 a = *(const bf16x8*)(WA + tap * 4096 + ks * 32);
#pragma unroll
        for (int t = 0; t < 4; ++t) {
          bf16x8 bt = *(const bf16x8*)(sPred + spt[t] * ROW + ks * 32 + q * 8);
          f[t] = __builtin_amdgcn_mfma_f32_16x16x32_bf16(a, bt, f[t], 0, 0, 0);
        }
      }
    }
#pragma unroll
    for (int t = 0; t < 4; ++t) {
      int p = t * 16 + n16;
      float v0 = fmaxf(f[t][0] + b_aff[co + 0], 0.f);
      float v1 = fmaxf(f[t][1] + b_aff[co + 1], 0.f);
      float v2 = fmaxf(f[t][2] + b_aff[co + 2], 0.f);
      float v3 = fmaxf(f[t][3] + b_aff[co + 3], 0.f);
      uint2 pk;
      pk.x = (unsigned)f2bf(v0) | ((unsigned)f2bf(v1) << 16);
      pk.y = (unsigned)f2bf(v2) | ((unsigned)f2bf(v3) << 16);
      *(uint2*)(sX + p * ROW2 + co) = pk;
    }
  }
  __syncthreads();

  // ---- agg conv: sX (128 ic: [a|x]) -> out. Swapped MFMA operands:
  // D rows = pixels, cols = oc  =>  lane owns 4 consecutive px of one oc
  // => coalesced float4 stores, single scalar bias.
  {
    f32x4 g[4] = {};
    const unsigned short* WG = Wt + 147456 + aw128;
#pragma unroll
    for (int tap = 0; tap < 9; ++tap) {
      const int dy = tap / 3 - 1, dx = tap % 3 - 1;
      int spt[4];
#pragma unroll
      for (int t = 0; t < 4; ++t) {
        int sy = pyt[t] + dy, sx = pxt[t] + dx;
        spt[t] = ((unsigned)sy < 8u && (unsigned)sx < 8u) ? (sy * 8 + sx) : 64;
      }
#pragma unroll
      for (int ks = 0; ks < 4; ++ks) {
        bf16x8 a = *(const bf16x8*)(WG + tap * 8192 + ks * 32);
#pragma unroll
        for (int t = 0; t < 4; ++t) {
          bf16x8 bt = *(const bf16x8*)(sX + spt[t] * ROW2 + ks * 32 + q * 8);
          g[t] = __builtin_amdgcn_mfma_f32_16x16x32_bf16(bt, a, g[t], 0, 0, 0);
        }
      }
    }
    float* ob = out + (size_t)img * IMGSZ;
    const float bg = b_agg[ocb + n16];
#pragma unroll
    for (int t = 0; t < 4; ++t) {
      f32x4 v;
#pragma unroll
      for (int r = 0; r < 4; ++r) v[r] = fmaxf(g[t][r] + bg, 0.f);
      *(f32x4*)(ob + (ocb + n16) * 64 + t * 16 + q * 4) = v;
    }
  }
}

// ---------------------------------------------------------------- fallback
__global__ __launch_bounds__(256) void k1(
    const float* __restrict__ x,
    const unsigned short* __restrict__ Wt,
    unsigned short* __restrict__ cA, unsigned short* __restrict__ cB)
{
  constexpr int ROW = 72;
  __shared__ __align__(16) unsigned short sX[65 * ROW];
  int b, o;
  decode_img(blockIdx.x, b, o);
  const int img = b * 16 + o;
  const int tid = threadIdx.x;
  const int w = tid >> 6, lane = tid & 63;

  stage_x<ROW>(x + (size_t)img * IMGSZ, sX, 0, w, lane);
  if (tid < 36) ((unsigned*)(sX + 64 * ROW))[tid] = 0;
  __syncthreads();

  const int q = lane >> 4, n16 = lane & 15;
  const int ocb = w * 16;
  const int co = ocb + q * 4;

  int pyt[4], pxt[4];
#pragma unroll
  for (int t = 0; t < 4; ++t) { int p = t * 16 + n16; pyt[t] = p >> 3; pxt[t] = p & 7; }

  f32x4 aA[4] = {}, aB[4] = {};
  const unsigned short* WA = Wt + 73728 + (ocb + n16) * 128 + q * 8;
  const unsigned short* WB = WA + 64;
#pragma unroll
  for (int tap = 0; tap < 9; ++tap) {
    const int dy = tap / 3 - 1, dx = tap % 3 - 1;
    int spt[4];
#pragma unroll
    for (int t = 0; t < 4; ++t) {
      int sy = pyt[t] + dy, sx = pxt[t] + dx;
      spt[t] = ((unsigned)sy < 8u && (unsigned)sx < 8u) ? (sy * 8 + sx) : 64;
    }
#pragma unroll
    for (int ks = 0; ks < 2; ++ks) {
      bf16x8 aa = *(const bf16x8*)(WA + tap * 8192 + ks * 32);
      bf16x8 ab = *(const bf16x8*)(WB + tap * 8192 + ks * 32);
#pragma unroll
      for (int t = 0; t < 4; ++t) {
        bf16x8 bt = *(const bf16x8*)(sX + spt[t] * ROW + ks * 32 + q * 8);
        aA[t] = __builtin_amdgcn_mfma_f32_16x16x32_bf16(aa, bt, aA[t], 0, 0, 0);
        aB[t] = __builtin_amdgcn_mfma_f32_16x16x32_bf16(ab, bt, aB[t], 0, 0, 0);
      }
    }
  }

  const size_t ib = (size_t)img * IMGSZ;
#pragma unroll
  for (int t = 0; t < 4; ++t) {
    int p = t * 16 + n16;
    uint2 pa, pb;
    pa.x = (unsigned)f2bf(aA[t][0]) | ((unsigned)f2bf(aA[t][1]) << 16);
    pa.y = (unsigned)f2bf(aA[t][2]) | ((unsigned)f2bf(aA[t][3]) << 16);
    pb.x = (unsigned)f2bf(aB[t][0]) | ((unsigned)f2bf(aB[t][1]) << 16);
    pb.y = (unsigned)f2bf(aB[t][2]) | ((unsigned)f2bf(aB[t][3]) << 16);
    *(uint2*)(cA + ib + p * 64 + co) = pa;
    *(uint2*)(cB + ib + p * 64 + co) = pb;
  }
}

__global__ __launch_bounds__(256, 2) void k2(
    const float* __restrict__ x,
    const int* __restrict__ g_idx,
    const unsigned short* __restrict__ Wt,
    const float* __restrict__ b_rel, const float* __restrict__ b_self,
    const float* __restrict__ b_aff, const float* __restrict__ b_agg,
    const unsigned short* __restrict__ cA, const unsigned short* __restrict__ cB,
    float* __restrict__ out)
{
  constexpr int ROW = 72, ROW2 = 136, XROW = 68;
  __shared__ __align__(16) unsigned short sX[65 * ROW2];
  __shared__ __align__(16) unsigned short sPred[65 * ROW];
  __shared__ __align__(16) float sXS[64 * XROW];
  __shared__ int so1[15], so2[15];
  __shared__ float sm[15];

  int b, i;
  decode_img(blockIdx.x, b, i);
  const int img = b * 16 + i;
  const int tid = threadIdx.x;
  const int w = tid >> 6, lane = tid & 63;

  if (tid < 15) {
    const int* gp = g_idx + ((size_t)b * 240 + i * 15 + tid) * 3;
    so1[tid] = gp[0] & 15;
    so2[tid] = gp[1] & 15;
    sm[tid]  = (float)gp[2];
  }

  stage_x<ROW2>(x + (size_t)img * IMGSZ, sX, 64, w, lane);
  if (tid < 68) ((unsigned*)(sX + 64 * ROW2))[tid] = 0;
  if (tid < 36) ((unsigned*)(sPred + 64 * ROW))[tid] = 0;
  __syncthreads();

  const int q = lane >> 4, n16 = lane & 15;
  const int ocb = w * 16;
  const int co = ocb + q * 4;
  const int aw64  = (ocb + n16) * 64 + q * 8;
  const int aw128 = (ocb + n16) * 128 + q * 8;

  int pyt[4], pxt[4];
#pragma unroll
  for (int t = 0; t < 4; ++t) { int p = t * 16 + n16; pyt[t] = p >> 3; pxt[t] = p & 7; }

  {
    f32x4 f[4] = {};
    const unsigned short* WS = Wt + aw64;
#pragma unroll
    for (int tap = 0; tap < 9; ++tap) {
      const int dy = tap / 3 - 1, dx = tap % 3 - 1;
      int spt[4];
#pragma unroll
      for (int t = 0; t < 4; ++t) {
        int sy = pyt[t] + dy, sx = pxt[t] + dx;
        spt[t] = ((unsigned)sy < 8u && (unsigned)sx < 8u) ? (sy * 8 + sx) : 64;
      }
#pragma unroll
      for (int ks = 0; ks < 2; ++ks) {
        bf16x8 a = *(const bf16x8*)(WS + tap * 4096 + ks * 32);
#pragma unroll
        for (int t = 0; t < 4; ++t) {
          bf16x8 bt = *(const bf16x8*)(sX + spt[t] * ROW2 + 64 + ks * 32 + q * 8);
          f[t] = __builtin_amdgcn_mfma_f32_16x16x32_bf16(a, bt, f[t], 0, 0, 0);
        }
      }
    }
#pragma unroll
    for (int t = 0; t < 4; ++t) {
      int p = t * 16 + n16;
      f32x4 vs = f[t];
#pragma unroll
      for (int r = 0; r < 4; ++r) vs[r] = fmaxf(vs[r] + b_self[co + r], 0.f);
      *(f32x4*)(sXS + p * XROW + co) = vs;
    }
  }
  __syncthreads();

  {
    const size_t bb = (size_t)b * 16 * IMGSZ;
#pragma unroll 1
    for (int pass = 0; pass < 4; ++pass) {
      const int e = tid * 4 + pass * 1024;
      const int e_px = e >> 6, e_ic = e & 63;
      uint2 v1[15], v2[15];
#pragma unroll
      for (int j = 0; j < 15; ++j) {
        v1[j] = *(const uint2*)(cA + bb + (size_t)so1[j] * IMGSZ + e);
        v2[j] = *(const uint2*)(cB + bb + (size_t)so2[j] * IMGSZ + e);
      }
      f32x4 xv = *(const f32x4*)(sXS + e_px * XROW + e_ic);
      float acc[4], br[4];
#pragma unroll
      for (int r = 0; r < 4; ++r) { br[r] = b_rel[e_ic + r]; acc[r] = xv[r]; }
#pragma unroll
      for (int j = 0; j < 15; ++j) {
        float m = sm[j];
        f32x4 a1 = bf4_to_f32(v1[j]);
        f32x4 a2 = bf4_to_f32(v2[j]);
#pragma unroll
        for (int r = 0; r < 4; ++r)
          acc[r] += fmaxf(m * (a1[r] + a2[r]) + br[r], 0.f);
      }
      uint2 pk;
      pk.x = (unsigned)f2bf(acc[0]) | ((unsigned)f2bf(acc[1]) << 16);
      pk.y = (unsigned)f2bf(acc[2]) | ((unsigned)f2bf(acc[3]) << 16);
      *(uint2*)(sPred + e_px * ROW + e_ic) = pk;
    }
  }
  __syncthreads();

  {
    f32x4 f[4] = {};
    const unsigned short* WA = Wt + 36864 + aw64;
#pragma unroll
    for (int tap = 0; tap < 9; ++tap) {
      const int dy = tap / 3 - 1, dx = tap % 3 - 1;
      int spt[4];
#pragma unroll
      for (int t = 0; t < 4; ++t) {
        int sy = pyt[t] + dy, sx = pxt[t] + dx;
        spt[t] = ((unsigned)sy < 8u && (unsigned)sx < 8u) ? (sy * 8 + sx) : 64;
      }
#pragma unroll
      for (int ks = 0; ks < 2; ++ks) {
        bf16x8 a = *(const bf16x8*)(WA + tap * 4096 + ks * 32);
#pragma unroll
        for (int t = 0; t < 4; ++t) {
          bf16x8 bt = *(const bf16x8*)(sPred + spt[t] * ROW + ks * 32 + q * 8);
          f[t] = __builtin_amdgcn_mfma_f32_16x16x32_bf16(a, bt, f[t], 0, 0, 0);
        }
      }
    }
#pragma unroll
    for (int t = 0; t < 4; ++t) {
      int p = t * 16 + n16;
      float v0 = fmaxf(f[t][0] + b_aff[co + 0], 0.f);
      float v1 = fmaxf(f[t][1] + b_aff[co + 1], 0.f);
      float v2 = fmaxf(f[t][2] + b_aff[co + 2], 0.f);
      float v3 = fmaxf(f[t][3] + b_aff[co + 3], 0.f);
      uint2 pk;
      pk.x = (unsigned)f2bf(v0) | ((unsigned)f2bf(v1) << 16);
      pk.y = (unsigned)f2bf(v2) | ((unsigned)f2bf(v3) << 16);
      *(uint2*)(sX + p * ROW2 + co) = pk;
    }
  }
  __syncthreads();

  {
    f32x4 g[4] = {};
    const unsigned short* WG = Wt + 147456 + aw128;
#pragma unroll
    for (int tap = 0; tap < 9; ++tap) {
      const int dy = tap / 3 - 1, dx = tap % 3 - 1;
      int spt[4];
#pragma unroll
      for (int t = 0; t < 4; ++t) {
        int sy = pyt[t] + dy, sx = pxt[t] + dx;
        spt[t] = ((unsigned)sy < 8u && (unsigned)sx < 8u) ? (sy * 8 + sx) : 64;
      }
#pragma unroll
      for (int ks = 0; ks < 4; ++ks) {
        bf16x8 a = *(const bf16x8*)(WG + tap * 8192 + ks * 32);
#pragma unroll
        for (int t = 0; t < 4; ++t) {
          bf16x8 bt = *(const bf16x8*)(sX + spt[t] * ROW2 + ks * 32 + q * 8);
          g[t] = __builtin_amdgcn_mfma_f32_16x16x32_bf16(a, bt, g[t], 0, 0, 0);
        }
      }
    }
    float* ob = out + (size_t)img * IMGSZ;
#pragma unroll
    for (int t = 0; t < 4; ++t) {
      int p = t * 16 + n16;
#pragma unroll
      for (int r = 0; r < 4; ++r)
        ob[(co + r) * 64 + p] = fmaxf(g[t][r] + b_agg[co + r], 0.f);
    }
  }
}

extern "C" void kernel_launch(void* const* d_in, const int* in_sizes, int n_in,
                              void* d_out, int out_size, void* d_ws, size_t ws_size,
                              hipStream_t stream) {
  const float* x      = (const float*)d_in[0];
  const int*   g_idx  = (const int*)  d_in[1];
  const float* W_rel  = (const float*)d_in[2];
  const float* b_rel  = (const float*)d_in[3];
  const float* W_self = (const float*)d_in[4];
  const float* b_self = (const float*)d_in[5];
  const float* W_aff  = (const float*)d_in[6];
  const float* b_aff  = (const float*)d_in[7];
  const float* W_agg  = (const float*)d_in[8];
  const float* b_agg  = (const float*)d_in[9];
  float* out = (float*)d_out;

  unsigned short* cA = (unsigned short*)d_ws;      // [512][64][64] bf16
  unsigned short* cB = cA + 2097152;
  unsigned short* Wt = cB + 2097152;               // 221184 bf16
  int* cnt = (int*)(Wt + 221184);                  // 32 batch counters, stride 32

  prep_w<<<864, 256, 0, stream>>>(W_rel, W_self, W_aff, W_agg, Wt, cnt);

  void* args[] = {(void*)&x, (void*)&g_idx, (void*)&Wt, (void*)&b_rel,
                  (void*)&b_self, (void*)&b_aff, (void*)&b_agg,
                  (void*)&cA, (void*)&cB, (void*)&cnt, (void*)&out};
  hipError_t ce = hipLaunchCooperativeKernel(
      reinterpret_cast<void*>(kfused), dim3(NIMG), dim3(256), args, 0, stream);
  if (ce != hipSuccess) {
    // fallback: proven 3-dispatch path (also taken if coop capture unsupported)
    k1<<<NIMG, 256, 0, stream>>>(x, Wt, cA, cB);
    k2<<<NIMG, 256, 0, stream>>>(x, g_idx, Wt, b_rel, b_self, b_aff, b_agg,
                                 cA, cB, out);
  }
}

// Round 2
// 117.407 us; speedup vs baseline: 2.1775x; 2.1775x over previous
//
#include <hip/hip_runtime.h>

// InterNet B=32,N=16,D=64,P=8. Factorized: conv(mask*[y1;y2],W_rel) =
// mask*(convA(x[o1]) + convB(x[o2])). 3 dispatches, no inter-block sync.
// (R17: cooperative-fusion experiment reverted -- agent-scope acquire spin
//  cost ~145us in L2 invalidate/writeback traffic on non-coherent XCD L2s.)
//   prep_w: weights -> bf16 Wt [tap][oc][ic]  (tiny)
//   k1: per image: stage x fp32 -> LDS bf16; relA/relB convs -> cA/cB  *bf16*
//   k2: per image: stage x -> LDS; self conv -> xs (LDS, fp32);
//       mask-compacted combine (only m=1 pairs load cA/cB; m=0 pairs fold
//       into (15-na)*relu(br)) -> pred(LDS) -> aff conv -> a(LDS[a|x]) ->
//       agg conv(128ic, swapped MFMA operands) -> coalesced float4 out
// New vs R15 (118us): combine compaction halves combine L2 traffic+VALU;
// agg epilogue 16 scalar stores -> 4 float4 stores (proven correct in R16).

#define NIMG 512
#define IMGSZ 4096

using bf16x8 = __attribute__((ext_vector_type(8))) short;
using f32x4  = __attribute__((ext_vector_type(4))) float;

__device__ inline unsigned short f2bf(float f) {
  union { float f; unsigned u; } v; v.f = f;
  unsigned r = v.u + 0x7fffu + ((v.u >> 16) & 1u);
  return (unsigned short)(r >> 16);
}

__device__ inline f32x4 bf4_to_f32(uint2 p) {
  union { unsigned u; float f; } c;
  f32x4 r;
  c.u = (p.x & 0xffffu) << 16;  r[0] = c.f;
  c.u = (p.x & 0xffff0000u);    r[1] = c.f;
  c.u = (p.y & 0xffffu) << 16;  r[2] = c.f;
  c.u = (p.y & 0xffff0000u);    r[3] = c.f;
  return r;
}

// Wt slots: self [9][64][64] @0, aff @36864, rel [9][64][128] @73728,
//           agg [9][64][128] @147456.
__global__ __launch_bounds__(256) void prep_w(
    const float* __restrict__ Wr, const float* __restrict__ Ws,
    const float* __restrict__ Wa, const float* __restrict__ Wg,
    unsigned short* __restrict__ Wt)
{
  int idx = blockIdx.x * 256 + threadIdx.x;
  if (idx >= 221184) return;
  float v;
  if (idx < 73728) {
    int c = idx / 36864, r = idx % 36864;
    int t = r >> 12, oc = (r >> 6) & 63, ic = r & 63;
    v = (c == 0 ? Ws : Wa)[oc * 576 + ic * 9 + t];
  } else {
    int r2 = idx - 73728;
    int half = r2 / 73728, rr = r2 % 73728;
    int t = rr >> 13, oc = (rr >> 7) & 63, ic = rr & 127;
    v = (half ? Wg : Wr)[oc * 1152 + ic * 9 + t];
  }
  Wt[idx] = f2bf(v);
}

// batch b pinned to XCD b&7 (perf heuristic; correctness never depends on it)
__device__ inline void decode_img(int j, int& b, int& o) {
  b = ((j >> 7) << 3) | (j & 7);
  o = (j >> 3) & 15;
}

// stage x (fp32 [ic][px]) -> LDS bf16 [px][stride ROWX], cols at +coff.
template<int ROWX>
__device__ inline void stage_x(const float* __restrict__ xb,
                               unsigned short* __restrict__ s,
                               int coff, int w, int px) {
#pragma unroll
  for (int r = 0; r < 8; ++r) {
    int ic0 = (w + 4 * r) * 2;
    const float* sp = xb + ic0 * 64;
    float a = sp[px], c = sp[64 + px];
    *(unsigned*)(s + px * ROWX + coff + ic0) =
        (unsigned)f2bf(a) | ((unsigned)f2bf(c) << 16);
  }
}

__global__ __launch_bounds__(256) void k1(
    const float* __restrict__ x,
    const unsigned short* __restrict__ Wt,
    unsigned short* __restrict__ cA, unsigned short* __restrict__ cB)
{
  constexpr int ROW = 72;
  __shared__ __align__(16) unsigned short sX[65 * ROW];
  int b, o;
  decode_img(blockIdx.x, b, o);
  const int img = b * 16 + o;
  const int tid = threadIdx.x;
  const int w = tid >> 6, lane = tid & 63;

  stage_x<ROW>(x + (size_t)img * IMGSZ, sX, 0, w, lane);
  if (tid < 36) ((unsigned*)(sX + 64 * ROW))[tid] = 0;
  __syncthreads();

  const int q = lane >> 4, n16 = lane & 15;
  const int ocb = w * 16;
  const int co = ocb + q * 4;

  int pyt[4], pxt[4];
#pragma unroll
  for (int t = 0; t < 4; ++t) { int p = t * 16 + n16; pyt[t] = p >> 3; pxt[t] = p & 7; }

  f32x4 aA[4] = {}, aB[4] = {};
  const unsigned short* WA = Wt + 73728 + (ocb + n16) * 128 + q * 8;  // rel ic 0..63
  const unsigned short* WB = WA + 64;                                 // rel ic 64..127
#pragma unroll
  for (int tap = 0; tap < 9; ++tap) {
    const int dy = tap / 3 - 1, dx = tap % 3 - 1;
    int spt[4];
#pragma unroll
    for (int t = 0; t < 4; ++t) {
      int sy = pyt[t] + dy, sx = pxt[t] + dx;
      spt[t] = ((unsigned)sy < 8u && (unsigned)sx < 8u) ? (sy * 8 + sx) : 64;
    }
#pragma unroll
    for (int ks = 0; ks < 2; ++ks) {
      bf16x8 aa = *(const bf16x8*)(WA + tap * 8192 + ks * 32);
      bf16x8 ab = *(const bf16x8*)(WB + tap * 8192 + ks * 32);
#pragma unroll
      for (int t = 0; t < 4; ++t) {
        bf16x8 bt = *(const bf16x8*)(sX + spt[t] * ROW + ks * 32 + q * 8);
        aA[t] = __builtin_amdgcn_mfma_f32_16x16x32_bf16(aa, bt, aA[t], 0, 0, 0);
        aB[t] = __builtin_amdgcn_mfma_f32_16x16x32_bf16(ab, bt, aB[t], 0, 0, 0);
      }
    }
  }

  const size_t ib = (size_t)img * IMGSZ;
#pragma unroll
  for (int t = 0; t < 4; ++t) {
    int p = t * 16 + n16;
    uint2 pa, pb;
    pa.x = (unsigned)f2bf(aA[t][0]) | ((unsigned)f2bf(aA[t][1]) << 16);
    pa.y = (unsigned)f2bf(aA[t][2]) | ((unsigned)f2bf(aA[t][3]) << 16);
    pb.x = (unsigned)f2bf(aB[t][0]) | ((unsigned)f2bf(aB[t][1]) << 16);
    pb.y = (unsigned)f2bf(aB[t][2]) | ((unsigned)f2bf(aB[t][3]) << 16);
    *(uint2*)(cA + ib + p * 64 + co) = pa;
    *(uint2*)(cB + ib + p * 64 + co) = pb;
  }
}

__global__ __launch_bounds__(256, 2) void k2(
    const float* __restrict__ x,
    const int* __restrict__ g_idx,
    const unsigned short* __restrict__ Wt,
    const float* __restrict__ b_rel, const float* __restrict__ b_self,
    const float* __restrict__ b_aff, const float* __restrict__ b_agg,
    const unsigned short* __restrict__ cA, const unsigned short* __restrict__ cB,
    float* __restrict__ out)
{
  constexpr int ROW = 72, ROW2 = 136, XROW = 68;
  __shared__ __align__(16) unsigned short sX[65 * ROW2];   // [a | x] bf16
  __shared__ __align__(16) unsigned short sPred[65 * ROW]; // pred bf16
  __shared__ __align__(16) float sXS[64 * XROW];           // xs fp32
  __shared__ int so1a[16], so2a[16];                        // compacted m=1 pairs
  __shared__ float sma[16];                                 // 1 active / 0 pad
  __shared__ int s_na;

  int b, i;
  decode_img(blockIdx.x, b, i);
  const int img = b * 16 + i;
  const int tid = threadIdx.x;
  const int w = tid >> 6, lane = tid & 63;

  // ---- mask compaction (wave 0): g_idx col2 is exactly 0/1 and uniform
  // per block. m=0 pairs contribute the constant relu(b_rel); only m=1
  // pairs need cA/cB loads. Ballot+prefix compacts them; pads are sma=0.
  int o1v = 0, o2v = 0, mv = 0;
  if (tid < 15) {
    const int* gp = g_idx + ((size_t)b * 240 + i * 15 + tid) * 3;
    o1v = gp[0] & 15;   // tile(x, n-1): x1[j] = x[j % 16]
    o2v = gp[1] & 15;
    mv  = gp[2];
  }
  if (tid < 64) {
    if (tid < 16) { so1a[tid] = 0; so2a[tid] = 0; sma[tid] = 0.f; }
    unsigned long long mk = __ballot(mv != 0);
    int pfx = (int)__popcll(mk & ((1ull << tid) - 1));
    if (mv) { so1a[pfx] = o1v; so2a[pfx] = o2v; sma[pfx] = 1.f; }
    if (tid == 0) s_na = (int)__popcll(mk);
  }

  stage_x<ROW2>(x + (size_t)img * IMGSZ, sX, 64, w, lane);
  if (tid < 68) ((unsigned*)(sX + 64 * ROW2))[tid] = 0;
  if (tid < 36) ((unsigned*)(sPred + 64 * ROW))[tid] = 0;
  __syncthreads();

  const int q = lane >> 4, n16 = lane & 15;
  const int ocb = w * 16;
  const int co = ocb + q * 4;
  const int aw64  = (ocb + n16) * 64 + q * 8;
  const int aw128 = (ocb + n16) * 128 + q * 8;

  int pyt[4], pxt[4];
#pragma unroll
  for (int t = 0; t < 4; ++t) { int p = t * 16 + n16; pyt[t] = p >> 3; pxt[t] = p & 7; }

  // ---- self conv (from staged x) -> xs in LDS fp32
  {
    f32x4 f[4] = {};
    const unsigned short* WS = Wt + aw64;
#pragma unroll
    for (int tap = 0; tap < 9; ++tap) {
      const int dy = tap / 3 - 1, dx = tap % 3 - 1;
      int spt[4];
#pragma unroll
      for (int t = 0; t < 4; ++t) {
        int sy = pyt[t] + dy, sx = pxt[t] + dx;
        spt[t] = ((unsigned)sy < 8u && (unsigned)sx < 8u) ? (sy * 8 + sx) : 64;
      }
#pragma unroll
      for (int ks = 0; ks < 2; ++ks) {
        bf16x8 a = *(const bf16x8*)(WS + tap * 4096 + ks * 32);
#pragma unroll
        for (int t = 0; t < 4; ++t) {
          bf16x8 bt = *(const bf16x8*)(sX + spt[t] * ROW2 + 64 + ks * 32 + q * 8);
          f[t] = __builtin_amdgcn_mfma_f32_16x16x32_bf16(a, bt, f[t], 0, 0, 0);
        }
      }
    }
#pragma unroll
    for (int t = 0; t < 4; ++t) {
      int p = t * 16 + n16;
      f32x4 vs = f[t];
#pragma unroll
      for (int r = 0; r < 4; ++r) vs[r] = fmaxf(vs[r] + b_self[co + r], 0.f);
      *(f32x4*)(sXS + p * XROW + co) = vs;
    }
  }
  __syncthreads();

  // ---- combine: pred = xs + (15-na)*relu(br)
  //                     + sum_{active j} relu(cA[o1_j]+cB[o2_j]+br)
  // chunks of 4 active pairs; 8 uint2 loads in flight per chunk.
  {
    const size_t bb = (size_t)b * 16 * IMGSZ;
    const int na = s_na;
    const int nc = (na + 3) >> 2;
    const float c0 = (float)(15 - na);
#pragma unroll 1
    for (int pass = 0; pass < 4; ++pass) {
      const int e = tid * 4 + pass * 1024;   // 4 consecutive [px][ic] elems
      const int e_px = e >> 6, e_ic = e & 63;
      f32x4 xv = *(const f32x4*)(sXS + e_px * XROW + e_ic);
      float acc[4], br[4];
#pragma unroll
      for (int r = 0; r < 4; ++r) {
        br[r] = b_rel[e_ic + r];
        acc[r] = xv[r] + c0 * fmaxf(br[r], 0.f);
      }
#pragma unroll 1
      for (int c = 0; c < nc; ++c) {
        uint2 v1[4], v2[4];
#pragma unroll
        for (int jj = 0; jj < 4; ++jj) {
          int j = c * 4 + jj;
          v1[jj] = *(const uint2*)(cA + bb + (size_t)so1a[j] * IMGSZ + e);
          v2[jj] = *(const uint2*)(cB + bb + (size_t)so2a[j] * IMGSZ + e);
        }
#pragma unroll
        for (int jj = 0; jj < 4; ++jj) {
          float s = sma[c * 4 + jj];   // active pairs have m==1; pads 0
          f32x4 a1 = bf4_to_f32(v1[jj]);
          f32x4 a2 = bf4_to_f32(v2[jj]);
#pragma unroll
          for (int r = 0; r < 4; ++r)
            acc[r] += s * fmaxf(a1[r] + a2[r] + br[r], 0.f);
        }
      }
      uint2 pk;
      pk.x = (unsigned)f2bf(acc[0]) | ((unsigned)f2bf(acc[1]) << 16);
      pk.y = (unsigned)f2bf(acc[2]) | ((unsigned)f2bf(acc[3]) << 16);
      *(uint2*)(sPred + e_px * ROW + e_ic) = pk;
    }
  }
  __syncthreads();

  // ---- aff conv: sPred -> a -> sX cols 0..63
  {
    f32x4 f[4] = {};
    const unsigned short* WA = Wt + 36864 + aw64;
#pragma unroll
    for (int tap = 0; tap < 9; ++tap) {
      const int dy = tap / 3 - 1, dx = tap % 3 - 1;
      int spt[4];
#pragma unroll
      for (int t = 0; t < 4; ++t) {
        int sy = pyt[t] + dy, sx = pxt[t] + dx;
        spt[t] = ((unsigned)sy < 8u && (unsigned)sx < 8u) ? (sy * 8 + sx) : 64;
      }
#pragma unroll
      for (int ks = 0; ks < 2; ++ks) {
        bf16x8 a = *(const bf16x8*)(WA + tap * 4096 + ks * 32);
#pragma unroll
        for (int t = 0; t < 4; ++t) {
          bf16x8 bt = *(const bf16x8*)(sPred + spt[t] * ROW + ks * 32 + q * 8);
          f[t] = __builtin_amdgcn_mfma_f32_16x16x32_bf16(a, bt, f[t], 0, 0, 0);
        }
      }
    }
#pragma unroll
    for (int t = 0; t < 4; ++t) {
      int p = t * 16 + n16;
      float v0 = fmaxf(f[t][0] + b_aff[co + 0], 0.f);
      float v1 = fmaxf(f[t][1] + b_aff[co + 1], 0.f);
      float v2 = fmaxf(f[t][2] + b_aff[co + 2], 0.f);
      float v3 = fmaxf(f[t][3] + b_aff[co + 3], 0.f);
      uint2 pk;
      pk.x = (unsigned)f2bf(v0) | ((unsigned)f2bf(v1) << 16);
      pk.y = (unsigned)f2bf(v2) | ((unsigned)f2bf(v3) << 16);
      *(uint2*)(sX + p * ROW2 + co) = pk;
    }
  }
  __syncthreads();

  // ---- agg conv: sX (128 ic: [a|x]) -> out. Swapped MFMA operands:
  // D rows = pixels, cols = oc  =>  lane owns 4 consecutive px of one oc
  // => coalesced float4 stores, single scalar bias. (correctness proven R16)
  {
    f32x4 g[4] = {};
    const unsigned short* WG = Wt + 147456 + aw128;
#pragma unroll
    for (int tap = 0; tap < 9; ++tap) {
      const int dy = tap / 3 - 1, dx = tap % 3 - 1;
      int spt[4];
#pragma unroll
      for (int t = 0; t < 4; ++t) {
        int sy = pyt[t] + dy, sx = pxt[t] + dx;
        spt[t] = ((unsigned)sy < 8u && (unsigned)sx < 8u) ? (sy * 8 + sx) : 64;
      }
#pragma unroll
      for (int ks = 0; ks < 4; ++ks) {
        bf16x8 a = *(const bf16x8*)(WG + tap * 8192 + ks * 32);
#pragma unroll
        for (int t = 0; t < 4; ++t) {
          bf16x8 bt = *(const bf16x8*)(sX + spt[t] * ROW2 + ks * 32 + q * 8);
          g[t] = __builtin_amdgcn_mfma_f32_16x16x32_bf16(bt, a, g[t], 0, 0, 0);
        }
      }
    }
    float* ob = out + (size_t)img * IMGSZ;
    const float bg = b_agg[ocb + n16];
#pragma unroll
    for (int t = 0; t < 4; ++t) {
      f32x4 v;
#pragma unroll
      for (int r = 0; r < 4; ++r) v[r] = fmaxf(g[t][r] + bg, 0.f);
      *(f32x4*)(ob + (ocb + n16) * 64 + t * 16 + q * 4) = v;
    }
  }
}

extern "C" void kernel_launch(void* const* d_in, const int* in_sizes, int n_in,
                              void* d_out, int out_size, void* d_ws, size_t ws_size,
                              hipStream_t stream) {
  const float* x      = (const float*)d_in[0];
  const int*   g_idx  = (const int*)  d_in[1];
  const float* W_rel  = (const float*)d_in[2];
  const float* b_rel  = (const float*)d_in[3];
  const float* W_self = (const float*)d_in[4];
  const float* b_self = (const float*)d_in[5];
  const float* W_aff  = (const float*)d_in[6];
  const float* b_aff  = (const float*)d_in[7];
  const float* W_agg  = (const float*)d_in[8];
  const float* b_agg  = (const float*)d_in[9];
  float* out = (float*)d_out;

  unsigned short* cA = (unsigned short*)d_ws;      // [512][64][64] bf16
  unsigned short* cB = cA + 2097152;
  unsigned short* Wt = cB + 2097152;               // 221184 bf16

  prep_w<<<864, 256, 0, stream>>>(W_rel, W_self, W_aff, W_agg, Wt);
  k1<<<NIMG, 256, 0, stream>>>(x, Wt, cA, cB);
  k2<<<NIMG, 256, 0, stream>>>(x, g_idx, Wt, b_rel, b_self, b_aff, b_agg,
                               cA, cB, out);
}

// Round 3
// 116.535 us; speedup vs baseline: 2.1937x; 1.0075x over previous
//
#include <hip/hip_runtime.h>

// InterNet B=32,N=16,D=64,P=8. Factorized: conv(mask*[y1;y2],W_rel) =
// mask*(convA(x[o1]) + convB(x[o2])). 3 dispatches, no inter-block sync.
// R18: occupancy push. k1/k2 were 8 waves/CU (25%) and latency-bound.
//   k1: 512-thr blocks, waves 0-3 = convA, waves 4-7 = convB (each loads only
//       its weight half -> no duplicated weight traffic). 16 waves/CU.
//   k2: 512-thr blocks; all 8 waves stage + combine (2 passes, 2x gather
//       parallelism); waves 4-7 idle at barriers during convs (conv-active
//       waves/CU unchanged). 2 blocks/CU: 90KB LDS, VGPR<=128 via (512,4).
//   prep_w: 4 elems/thread, uint2 stores.
// Arithmetic identical to R17 (absmax must stay 0.0625).

#define NIMG 512
#define IMGSZ 4096

using bf16x8 = __attribute__((ext_vector_type(8))) short;
using f32x4  = __attribute__((ext_vector_type(4))) float;

__device__ inline unsigned short f2bf(float f) {
  union { float f; unsigned u; } v; v.f = f;
  unsigned r = v.u + 0x7fffu + ((v.u >> 16) & 1u);
  return (unsigned short)(r >> 16);
}

__device__ inline f32x4 bf4_to_f32(uint2 p) {
  union { unsigned u; float f; } c;
  f32x4 r;
  c.u = (p.x & 0xffffu) << 16;  r[0] = c.f;
  c.u = (p.x & 0xffff0000u);    r[1] = c.f;
  c.u = (p.y & 0xffffu) << 16;  r[2] = c.f;
  c.u = (p.y & 0xffff0000u);    r[3] = c.f;
  return r;
}

// Wt slots: self [9][64][64] @0, aff @36864, rel [9][64][128] @73728,
//           agg [9][64][128] @147456.
__global__ __launch_bounds__(256) void prep_w(
    const float* __restrict__ Wr, const float* __restrict__ Ws,
    const float* __restrict__ Wa, const float* __restrict__ Wg,
    unsigned short* __restrict__ Wt)
{
  int i4 = (blockIdx.x * 256 + threadIdx.x) * 4;
  if (i4 >= 221184) return;
  unsigned short o4[4];
#pragma unroll
  for (int e = 0; e < 4; ++e) {
    int idx = i4 + e;
    float v;
    if (idx < 73728) {
      int c = idx / 36864, r = idx % 36864;
      int t = r >> 12, oc = (r >> 6) & 63, ic = r & 63;
      v = (c == 0 ? Ws : Wa)[oc * 576 + ic * 9 + t];
    } else {
      int r2 = idx - 73728;
      int half = r2 / 73728, rr = r2 % 73728;
      int t = rr >> 13, oc = (rr >> 7) & 63, ic = rr & 127;
      v = (half ? Wg : Wr)[oc * 1152 + ic * 9 + t];
    }
    o4[e] = f2bf(v);
  }
  uint2 pk;
  pk.x = (unsigned)o4[0] | ((unsigned)o4[1] << 16);
  pk.y = (unsigned)o4[2] | ((unsigned)o4[3] << 16);
  *(uint2*)(Wt + i4) = pk;
}

// batch b pinned to XCD b&7 (perf heuristic; correctness never depends on it)
__device__ inline void decode_img(int j, int& b, int& o) {
  b = ((j >> 7) << 3) | (j & 7);
  o = (j >> 3) & 15;
}

// stage x (fp32 [ic][px]) -> LDS bf16 [px][stride ROWX], cols at +coff.
// 512-thread version: each thread writes 4 u32 (8 ic-values) for its px.
template<int ROWX>
__device__ inline void stage_x512(const float* __restrict__ xb,
                                  unsigned short* __restrict__ s,
                                  int coff, int w8, int px) {
#pragma unroll
  for (int r = 0; r < 4; ++r) {
    int ic0 = (w8 + 8 * r) * 2;
    const float* sp = xb + ic0 * 64;
    float a = sp[px], c = sp[64 + px];
    *(unsigned*)(s + px * ROWX + coff + ic0) =
        (unsigned)f2bf(a) | ((unsigned)f2bf(c) << 16);
  }
}

__global__ __launch_bounds__(512, 4) void k1(
    const float* __restrict__ x,
    const unsigned short* __restrict__ Wt,
    unsigned short* __restrict__ cA, unsigned short* __restrict__ cB)
{
  constexpr int ROW = 72;
  __shared__ __align__(16) unsigned short sX[65 * ROW];
  int b, o;
  decode_img(blockIdx.x, b, o);
  const int img = b * 16 + o;
  const int tid = threadIdx.x;
  const int w8 = tid >> 6, lane = tid & 63;

  stage_x512<ROW>(x + (size_t)img * IMGSZ, sX, 0, w8, lane);
  if (tid < 36) ((unsigned*)(sX + 64 * ROW))[tid] = 0;
  __syncthreads();

  const int half = tid >> 8;       // waves 0-3: convA (ic 0..63); 4-7: convB
  const int w = w8 & 3;            // oc quarter
  const int q = lane >> 4, n16 = lane & 15;
  const int ocb = w * 16;
  const int co = ocb + q * 4;

  int pyt[4], pxt[4];
#pragma unroll
  for (int t = 0; t < 4; ++t) { int p = t * 16 + n16; pyt[t] = p >> 3; pxt[t] = p & 7; }

  f32x4 acc[4] = {};
  const unsigned short* WH = Wt + 73728 + (ocb + n16) * 128 + q * 8 + half * 64;
#pragma unroll
  for (int tap = 0; tap < 9; ++tap) {
    const int dy = tap / 3 - 1, dx = tap % 3 - 1;
    int spt[4];
#pragma unroll
    for (int t = 0; t < 4; ++t) {
      int sy = pyt[t] + dy, sx = pxt[t] + dx;
      spt[t] = ((unsigned)sy < 8u && (unsigned)sx < 8u) ? (sy * 8 + sx) : 64;
    }
#pragma unroll
    for (int ks = 0; ks < 2; ++ks) {
      bf16x8 aa = *(const bf16x8*)(WH + tap * 8192 + ks * 32);
#pragma unroll
      for (int t = 0; t < 4; ++t) {
        bf16x8 bt = *(const bf16x8*)(sX + spt[t] * ROW + ks * 32 + q * 8);
        acc[t] = __builtin_amdgcn_mfma_f32_16x16x32_bf16(aa, bt, acc[t], 0, 0, 0);
      }
    }
  }

  unsigned short* dst = half ? cB : cA;
  const size_t ib = (size_t)img * IMGSZ;
#pragma unroll
  for (int t = 0; t < 4; ++t) {
    int p = t * 16 + n16;
    uint2 pa;
    pa.x = (unsigned)f2bf(acc[t][0]) | ((unsigned)f2bf(acc[t][1]) << 16);
    pa.y = (unsigned)f2bf(acc[t][2]) | ((unsigned)f2bf(acc[t][3]) << 16);
    *(uint2*)(dst + ib + p * 64 + co) = pa;
  }
}

__global__ __launch_bounds__(512, 4) void k2(
    const float* __restrict__ x,
    const int* __restrict__ g_idx,
    const unsigned short* __restrict__ Wt,
    const float* __restrict__ b_rel, const float* __restrict__ b_self,
    const float* __restrict__ b_aff, const float* __restrict__ b_agg,
    const unsigned short* __restrict__ cA, const unsigned short* __restrict__ cB,
    float* __restrict__ out)
{
  constexpr int ROW = 72, ROW2 = 136, XROW = 68;
  __shared__ __align__(16) unsigned short sX[65 * ROW2];   // [a | x] bf16
  __shared__ __align__(16) unsigned short sPred[65 * ROW]; // pred bf16
  __shared__ __align__(16) float sXS[64 * XROW];           // xs fp32
  __shared__ int so1a[16], so2a[16];                        // compacted m=1 pairs
  __shared__ float sma[16];                                 // 1 active / 0 pad
  __shared__ int s_na;

  int b, i;
  decode_img(blockIdx.x, b, i);
  const int img = b * 16 + i;
  const int tid = threadIdx.x;
  const int w8 = tid >> 6, lane = tid & 63;

  // ---- mask compaction (wave 0): g_idx col2 is exactly 0/1, block-uniform.
  // m=0 pairs fold into the constant (15-na)*relu(br); only m=1 pairs load.
  int o1v = 0, o2v = 0, mv = 0;
  if (tid < 15) {
    const int* gp = g_idx + ((size_t)b * 240 + i * 15 + tid) * 3;
    o1v = gp[0] & 15;   // tile(x, n-1): x1[j] = x[j % 16]
    o2v = gp[1] & 15;
    mv  = gp[2];
  }
  if (tid < 64) {
    if (tid < 16) { so1a[tid] = 0; so2a[tid] = 0; sma[tid] = 0.f; }
    unsigned long long mk = __ballot(mv != 0);
    int pfx = (int)__popcll(mk & ((1ull << tid) - 1));
    if (mv) { so1a[pfx] = o1v; so2a[pfx] = o2v; sma[pfx] = 1.f; }
    if (tid == 0) s_na = (int)__popcll(mk);
  }

  stage_x512<ROW2>(x + (size_t)img * IMGSZ, sX, 64, w8, lane);
  if (tid < 68) ((unsigned*)(sX + 64 * ROW2))[tid] = 0;
  if (tid < 36) ((unsigned*)(sPred + 64 * ROW))[tid] = 0;
  __syncthreads();

  const int w = w8 & 3;
  const int q = lane >> 4, n16 = lane & 15;
  const int ocb = w * 16;
  const int co = ocb + q * 4;
  const int aw64  = (ocb + n16) * 64 + q * 8;
  const int aw128 = (ocb + n16) * 128 + q * 8;

  int pyt[4], pxt[4];
#pragma unroll
  for (int t = 0; t < 4; ++t) { int p = t * 16 + n16; pyt[t] = p >> 3; pxt[t] = p & 7; }

  // ---- self conv (waves 0-3) -> xs in LDS fp32
  if (tid < 256) {
    f32x4 f[4] = {};
    const unsigned short* WS = Wt + aw64;
#pragma unroll
    for (int tap = 0; tap < 9; ++tap) {
      const int dy = tap / 3 - 1, dx = tap % 3 - 1;
      int spt[4];
#pragma unroll
      for (int t = 0; t < 4; ++t) {
        int sy = pyt[t] + dy, sx = pxt[t] + dx;
        spt[t] = ((unsigned)sy < 8u && (unsigned)sx < 8u) ? (sy * 8 + sx) : 64;
      }
#pragma unroll
      for (int ks = 0; ks < 2; ++ks) {
        bf16x8 a = *(const bf16x8*)(WS + tap * 4096 + ks * 32);
#pragma unroll
        for (int t = 0; t < 4; ++t) {
          bf16x8 bt = *(const bf16x8*)(sX + spt[t] * ROW2 + 64 + ks * 32 + q * 8);
          f[t] = __builtin_amdgcn_mfma_f32_16x16x32_bf16(a, bt, f[t], 0, 0, 0);
        }
      }
    }
#pragma unroll
    for (int t = 0; t < 4; ++t) {
      int p = t * 16 + n16;
      f32x4 vs = f[t];
#pragma unroll
      for (int r = 0; r < 4; ++r) vs[r] = fmaxf(vs[r] + b_self[co + r], 0.f);
      *(f32x4*)(sXS + p * XROW + co) = vs;
    }
  }
  __syncthreads();

  // ---- combine (all 8 waves, 2 passes): pred = xs + (15-na)*relu(br)
  //                     + sum_{active j} relu(cA[o1_j]+cB[o2_j]+br)
  {
    const size_t bb = (size_t)b * 16 * IMGSZ;
    const int na = s_na;
    const int nc = (na + 3) >> 2;
    const float c0 = (float)(15 - na);
#pragma unroll 1
    for (int pass = 0; pass < 2; ++pass) {
      const int e = tid * 4 + pass * 2048;   // 4 consecutive [px][ic] elems
      const int e_px = e >> 6, e_ic = e & 63;
      f32x4 xv = *(const f32x4*)(sXS + e_px * XROW + e_ic);
      float acc[4], br[4];
#pragma unroll
      for (int r = 0; r < 4; ++r) {
        br[r] = b_rel[e_ic + r];
        acc[r] = xv[r] + c0 * fmaxf(br[r], 0.f);
      }
#pragma unroll 1
      for (int c = 0; c < nc; ++c) {
        uint2 v1[4], v2[4];
#pragma unroll
        for (int jj = 0; jj < 4; ++jj) {
          int j = c * 4 + jj;
          v1[jj] = *(const uint2*)(cA + bb + (size_t)so1a[j] * IMGSZ + e);
          v2[jj] = *(const uint2*)(cB + bb + (size_t)so2a[j] * IMGSZ + e);
        }
#pragma unroll
        for (int jj = 0; jj < 4; ++jj) {
          float s = sma[c * 4 + jj];   // active pairs have m==1; pads 0
          f32x4 a1 = bf4_to_f32(v1[jj]);
          f32x4 a2 = bf4_to_f32(v2[jj]);
#pragma unroll
          for (int r = 0; r < 4; ++r)
            acc[r] += s * fmaxf(a1[r] + a2[r] + br[r], 0.f);
        }
      }
      uint2 pk;
      pk.x = (unsigned)f2bf(acc[0]) | ((unsigned)f2bf(acc[1]) << 16);
      pk.y = (unsigned)f2bf(acc[2]) | ((unsigned)f2bf(acc[3]) << 16);
      *(uint2*)(sPred + e_px * ROW + e_ic) = pk;
    }
  }
  __syncthreads();

  // ---- aff conv (waves 0-3): sPred -> a -> sX cols 0..63
  if (tid < 256) {
    f32x4 f[4] = {};
    const unsigned short* WA = Wt + 36864 + aw64;
#pragma unroll
    for (int tap = 0; tap < 9; ++tap) {
      const int dy = tap / 3 - 1, dx = tap % 3 - 1;
      int spt[4];
#pragma unroll
      for (int t = 0; t < 4; ++t) {
        int sy = pyt[t] + dy, sx = pxt[t] + dx;
        spt[t] = ((unsigned)sy < 8u && (unsigned)sx < 8u) ? (sy * 8 + sx) : 64;
      }
#pragma unroll
      for (int ks = 0; ks < 2; ++ks) {
        bf16x8 a = *(const bf16x8*)(WA + tap * 4096 + ks * 32);
#pragma unroll
        for (int t = 0; t < 4; ++t) {
          bf16x8 bt = *(const bf16x8*)(sPred + spt[t] * ROW + ks * 32 + q * 8);
          f[t] = __builtin_amdgcn_mfma_f32_16x16x32_bf16(a, bt, f[t], 0, 0, 0);
        }
      }
    }
#pragma unroll
    for (int t = 0; t < 4; ++t) {
      int p = t * 16 + n16;
      float v0 = fmaxf(f[t][0] + b_aff[co + 0], 0.f);
      float v1 = fmaxf(f[t][1] + b_aff[co + 1], 0.f);
      float v2 = fmaxf(f[t][2] + b_aff[co + 2], 0.f);
      float v3 = fmaxf(f[t][3] + b_aff[co + 3], 0.f);
      uint2 pk;
      pk.x = (unsigned)f2bf(v0) | ((unsigned)f2bf(v1) << 16);
      pk.y = (unsigned)f2bf(v2) | ((unsigned)f2bf(v3) << 16);
      *(uint2*)(sX + p * ROW2 + co) = pk;
    }
  }
  __syncthreads();

  // ---- agg conv (waves 0-3): sX (128 ic: [a|x]) -> out. Swapped MFMA
  // operands: lane owns 4 consecutive px of one oc -> coalesced float4.
  if (tid < 256) {
    f32x4 g[4] = {};
    const unsigned short* WG = Wt + 147456 + aw128;
#pragma unroll
    for (int tap = 0; tap < 9; ++tap) {
      const int dy = tap / 3 - 1, dx = tap % 3 - 1;
      int spt[4];
#pragma unroll
      for (int t = 0; t < 4; ++t) {
        int sy = pyt[t] + dy, sx = pxt[t] + dx;
        spt[t] = ((unsigned)sy < 8u && (unsigned)sx < 8u) ? (sy * 8 + sx) : 64;
      }
#pragma unroll
      for (int ks = 0; ks < 4; ++ks) {
        bf16x8 a = *(const bf16x8*)(WG + tap * 8192 + ks * 32);
#pragma unroll
        for (int t = 0; t < 4; ++t) {
          bf16x8 bt = *(const bf16x8*)(sX + spt[t] * ROW2 + ks * 32 + q * 8);
          g[t] = __builtin_amdgcn_mfma_f32_16x16x32_bf16(bt, a, g[t], 0, 0, 0);
        }
      }
    }
    float* ob = out + (size_t)img * IMGSZ;
    const float bg = b_agg[ocb + n16];
#pragma unroll
    for (int t = 0; t < 4; ++t) {
      f32x4 v;
#pragma unroll
      for (int r = 0; r < 4; ++r) v[r] = fmaxf(g[t][r] + bg, 0.f);
      *(f32x4*)(ob + (ocb + n16) * 64 + t * 16 + q * 4) = v;
    }
  }
}

extern "C" void kernel_launch(void* const* d_in, const int* in_sizes, int n_in,
                              void* d_out, int out_size, void* d_ws, size_t ws_size,
                              hipStream_t stream) {
  const float* x      = (const float*)d_in[0];
  const int*   g_idx  = (const int*)  d_in[1];
  const float* W_rel  = (const float*)d_in[2];
  const float* b_rel  = (const float*)d_in[3];
  const float* W_self = (const float*)d_in[4];
  const float* b_self = (const float*)d_in[5];
  const float* W_aff  = (const float*)d_in[6];
  const float* b_aff  = (const float*)d_in[7];
  const float* W_agg  = (const float*)d_in[8];
  const float* b_agg  = (const float*)d_in[9];
  float* out = (float*)d_out;

  unsigned short* cA = (unsigned short*)d_ws;      // [512][64][64] bf16
  unsigned short* cB = cA + 2097152;
  unsigned short* Wt = cB + 2097152;               // 221184 bf16

  prep_w<<<216, 256, 0, stream>>>(W_rel, W_self, W_aff, W_agg, Wt);
  k1<<<NIMG, 512, 0, stream>>>(x, Wt, cA, cB);
  k2<<<NIMG, 512, 0, stream>>>(x, g_idx, Wt, b_rel, b_self, b_aff, b_agg,
                               cA, cB, out);
}